// Round 6
// baseline (93.152 us; speedup 1.0000x reference)
//
#include <hip/hip_runtime.h>

typedef float  v4f    __attribute__((ext_vector_type(4)));
typedef float  f32x4  __attribute__((ext_vector_type(4)));
typedef short  bf16x8 __attribute__((ext_vector_type(8)));
typedef short  bf16x4 __attribute__((ext_vector_type(4)));

namespace {
constexpr int XBSTR = 264;   // xbf row stride (bf16)
constexpr int XDSTR = 68;    // xd row stride (f32)
constexpr int MWSTR = 132;   // mw row stride (f32)
constexpr int ASTR  = 264;   // att row stride (f32)
constexpr int MSTR  = 72;    // mbf/abf row stride (bf16)
constexpr int NBAT  = 4;
constexpr int FRAG_SLOTS = 5120;          // 16B slots in d_ws frag table

__device__ __forceinline__ float fsilu(float v){ return v/(1.f+__expf(-v)); }
__device__ __forceinline__ float fsigm(float v){ return 1.f/(1.f+__expf(-v)); }
__device__ __forceinline__ short f2bf(float f){          // fp32 -> bf16 RNE
  unsigned u = __builtin_bit_cast(unsigned, f);
  return (short)((u + 0x7FFFu + ((u>>16)&1u)) >> 16);
}

// ---- B-fragment getters: frag table in ws (fast) or on-the-fly (fallback) ----
template<bool USE_WS>
__device__ __forceinline__ bf16x8 get_bd(const bf16x8* wsf, const float* Wd,
                                         int nt, int ks, int l){
  if constexpr (USE_WS) return wsf[(nt*8 + ks)*64 + l];
  bf16x8 f;
  #pragma unroll
  for (int j = 0; j < 8; ++j) f[j] = f2bf(Wd[(ks*32 + (l>>4)*8 + j)*64 + nt*16 + (l&15)]);
  return f;
}
template<bool USE_WS>
__device__ __forceinline__ bf16x8 get_bc(const bf16x8* wsf, const float* Wc,
                                         int nt, int ks, int l){
  if constexpr (USE_WS) return wsf[2048 + (nt*2 + ks)*64 + l];
  const int col = nt*16 + (l&15), cw = col>>6, co = col&63;
  bf16x8 f;
  #pragma unroll
  for (int j = 0; j < 8; ++j) f[j] = f2bf(Wc[co*128 + cw*64 + ks*32 + (l>>4)*8 + j]);
  return f;
}
template<bool USE_WS>
__device__ __forceinline__ bf16x8 get_ba(const bf16x8* wsf, const float* Wa,
                                         int nt, int ks, int l){
  if constexpr (USE_WS) return wsf[3072 + (nt*2 + ks)*64 + l];
  const int col = nt*16 + (l&15);
  bf16x8 f;
  #pragma unroll
  for (int j = 0; j < 8; ++j) f[j] = f2bf(Wa[(ks*32 + (l>>4)*8 + j)*256 + col]);
  return f;
}
}

// ---- pre-kernel: pack Wd/Wc/Wa into bf16 MFMA B-fragment tables in ws ----
__global__ __launch_bounds__(256)
void pack_frags(const float* __restrict__ Wd, const float* __restrict__ Wc,
                const float* __restrict__ Wa, bf16x8* __restrict__ wsf)
{
  const int e  = blockIdx.x*256 + threadIdx.x;      // 0..5119
  const int l  = e & 63;
  const int fi = e >> 6;                            // 0..79
  bf16x8 f;
  if (fi < 32) {                                    // Bd: nt(4) x ks(8)
    const int nt = fi >> 3, ks = fi & 7;
    #pragma unroll
    for (int j = 0; j < 8; ++j) f[j] = f2bf(Wd[(ks*32 + (l>>4)*8 + j)*64 + nt*16 + (l&15)]);
  } else if (fi < 48) {                             // Bc: nt(8) x ks(2)
    const int idx = fi - 32, nt = idx >> 1, ks = idx & 1;
    const int col = nt*16 + (l&15), cw = col>>6, co = col&63;
    #pragma unroll
    for (int j = 0; j < 8; ++j) f[j] = f2bf(Wc[co*128 + cw*64 + ks*32 + (l>>4)*8 + j]);
  } else {                                          // Ba: nt(16) x ks(2)
    const int idx = fi - 48, nt = idx >> 1, ks = idx & 1;
    const int col = nt*16 + (l&15);
    #pragma unroll
    for (int j = 0; j < 8; ++j) f[j] = f2bf(Wa[(ks*32 + (l>>4)*8 + j)*256 + col]);
  }
  wsf[e] = f;
}

template<bool USE_WS>
__global__ __launch_bounds__(256, 4)
void fused_gnn_v5(const float* __restrict__ x,
                  const float* __restrict__ Wd, const float* __restrict__ bd,
                  const float* __restrict__ bn1s, const float* __restrict__ bn1b,
                  const float* __restrict__ bn1m, const float* __restrict__ bn1v,
                  const float* __restrict__ Wc,
                  const float* __restrict__ bn2s, const float* __restrict__ bn2b,
                  const float* __restrict__ bn2m, const float* __restrict__ bn2v,
                  const float* __restrict__ Wa, const float* __restrict__ ba,
                  const bf16x8* __restrict__ wsf,
                  float* __restrict__ out, int nbat)
{
  __shared__ short xbf[18*XBSTR];       // bf16 x tile; rows 17 = scratch (discarded MFMA rows)
  __shared__ float uni[5*ASTR];         // union: xd f32[17][68] | att f32[5][264]
  __shared__ float mw [5*MWSTR];
  __shared__ short mbf[16*MSTR];        // rows 5..15 garbage (discarded MFMA rows)
  __shared__ short abf[16*MSTR];
  __shared__ float a1c[64], b1c[64], a2c[64], b2c[64];

  float* xd  = uni;
  float* att = uni;

  const int tid  = threadIdx.x;
  const int l    = tid & 63;
  const int wv   = tid >> 6;            // wave 0..3
  const int arow = l & 15;
  const int ak8  = (l >> 4) * 8;

  // ---- one-time: fold BN affines (b_down folded into bn1 bias) ----
  if (tid < 64) {
    float av = bn1s[tid] * rsqrtf(bn1v[tid] + 1e-5f);
    a1c[tid] = av; b1c[tid] = (bd[tid] - bn1m[tid])*av + bn1b[tid];
    float av2 = bn2s[tid] * rsqrtf(bn2v[tid] + 1e-5f);
    a2c[tid] = av2; b2c[tid] = bn2b[tid] - bn2m[tid]*av2;
  }

  // ---- persistent: phase-A weight fragments (n-tile = wv), 32 VGPR ----
  bf16x8 Bd[8];
  #pragma unroll
  for (int ks = 0; ks < 8; ++ks) Bd[ks] = get_bd<USE_WS>(wsf, Wd, wv, ks, l);
  const int colA = wv*16 + arow;
  // phase-E bias values for this wave's 4 n-tiles
  float bav[4];
  #pragma unroll
  for (int t = 0; t < 4; ++t) bav[t] = ba[wv*64 + t*16 + arow];

  // ---- prefetch batch 0 into regs (T14) ----
  const v4f* x4 = (const v4f*)x;
  v4f xr0, xr1, xr2, xr3, xr4;
  {
    const size_t b4 = (size_t)(blockIdx.x*nbat) * 1088;
    xr0 = x4[b4 + tid];       xr1 = x4[b4 + 256 + tid];
    xr2 = x4[b4 + 512 + tid]; xr3 = x4[b4 + 768 + tid];
    if (tid < 64) xr4 = x4[b4 + 1024 + tid];
  }

  for (int it = 0; it < nbat; ++it) {
    const int batch = blockIdx.x*nbat + it;

    // ---- stage: regs -> bf16 LDS (one conversion per element) ----
    {
      auto store4 = [&](v4f v, int e){
        const int r = e >> 6, c4 = (e & 63) * 4;
        bf16x4 b; b[0]=f2bf(v.x); b[1]=f2bf(v.y); b[2]=f2bf(v.z); b[3]=f2bf(v.w);
        *(bf16x4*)&xbf[r*XBSTR + c4] = b;
      };
      store4(xr0, tid);        store4(xr1, 256 + tid);
      store4(xr2, 512 + tid);  store4(xr3, 768 + tid);
      if (tid < 64) store4(xr4, 1024 + tid);
    }
    // issue next batch's loads (overlap with this iter's compute)
    if (it + 1 < nbat) {
      const size_t b4 = (size_t)(batch + 1) * 1088;
      xr0 = x4[b4 + tid];       xr1 = x4[b4 + 256 + tid];
      xr2 = x4[b4 + 512 + tid]; xr3 = x4[b4 + 768 + tid];
      if (tid < 64) xr4 = x4[b4 + 1024 + tid];
    }
    __syncthreads();                                   // barrier 1: stage -> A

    // ---- Phase A (MFMA): xd = silu(bn1(x @ Wd)), rows 0..16, N=64, K=256 ----
    {
      f32x4 acc0 = {0.f,0.f,0.f,0.f};                  // rows 0..15
      f32x4 acc1 = {0.f,0.f,0.f,0.f};                  // tail: tile-row 0 = batch row 16
      const int rowT = (arow == 0) ? 16 : 17;          // rows 1..15 of tail tile discarded
      #pragma unroll
      for (int ks = 0; ks < 8; ++ks) {
        bf16x8 a0 = *(const bf16x8*)&xbf[arow*XBSTR + ks*32 + ak8];
        acc0 = __builtin_amdgcn_mfma_f32_16x16x32_bf16(a0, Bd[ks], acc0, 0, 0, 0);
        bf16x8 a1 = *(const bf16x8*)&xbf[rowT*XBSTR + ks*32 + ak8];
        acc1 = __builtin_amdgcn_mfma_f32_16x16x32_bf16(a1, Bd[ks], acc1, 0, 0, 0);
      }
      const float av = a1c[colA], bv = b1c[colA];
      #pragma unroll
      for (int j = 0; j < 4; ++j) {
        const int r = (l>>4)*4 + j;
        xd[r*XDSTR + colA] = fsilu(acc0[j]*av + bv);
      }
      if ((l >> 4) == 0)
        xd[16*XDSTR + colA] = fsilu(acc1[0]*av + bv);
    }
    __syncthreads();                                   // barrier 2: A -> B1 (xd cross-wave)

    // ---- Phase B1: group means (redundant per wave; identical bits) ----
    #pragma unroll
    for (int g = 0; g < 5; ++g) {
      const int i = l;
      float m;
      if (g == 0) {
        m = (xd[0*XDSTR+i]+xd[1*XDSTR+i]+xd[2*XDSTR+i]
            +xd[3*XDSTR+i]+xd[4*XDSTR+i])*0.2f;
      } else {
        const int kb = (g==1)?5:(g==2)?6:(g==3)?11:12;
        m = (xd[kb*XDSTR+i] + xd[(kb+2)*XDSTR+i] + xd[(kb+4)*XDSTR+i])*(1.f/3.f);
      }
      mbf[g*MSTR + i] = f2bf(m);
    }
    // no barrier: B2 reads this wave's own mbf writes (lgkmcnt-ordered)

    // ---- Phase B2 (MFMA): mw = means @ [Wc1|Wc2], M=5, N=128 (wave-split), K=64 ----
    {
      bf16x8 am[2];
      #pragma unroll
      for (int ks = 0; ks < 2; ++ks)
        am[ks] = *(const bf16x8*)&mbf[arow*MSTR + ks*32 + ak8];
      #pragma unroll
      for (int t = 0; t < 2; ++t) {
        const int nt = wv*2 + t;
        f32x4 acc = {0.f,0.f,0.f,0.f};
        #pragma unroll
        for (int ks = 0; ks < 2; ++ks)
          acc = __builtin_amdgcn_mfma_f32_16x16x32_bf16(
                  am[ks], get_bc<USE_WS>(wsf, Wc, nt, ks, l), acc, 0, 0, 0);
        #pragma unroll
        for (int j = 0; j < 4; ++j) {
          const int g = (l>>4)*4 + j;
          if (g < 5) mw[g*MWSTR + nt*16 + arow] = acc[j];
        }
      }
    }
    __syncthreads();                                   // barrier 3: B2 -> B3 (mw cross-wave)

    // ---- Phase B3: agg (redundant per wave) ----
    #pragma unroll
    for (int g = 0; g < 5; ++g) {
      const int o = l;
      const float bse = mw[g*MWSTR + o] - mw[g*MWSTR + 64 + o];
      const float av = a2c[o], bv = b2c[o];
      float s = 0.f;
      #pragma unroll
      for (int cc = 0; cc < 5; ++cc) {
        if (cc != g) s += fsilu((bse + mw[cc*MWSTR + 64 + o])*av + bv);
      }
      abf[g*MSTR + o] = f2bf(s);
    }
    // no barrier: E reads this wave's own abf writes

    // ---- Phase E (MFMA): att = sigmoid(agg @ Wa + ba), M=5, N=256 (wave-split), K=64 ----
    {
      bf16x8 ae[2];
      #pragma unroll
      for (int ks = 0; ks < 2; ++ks)
        ae[ks] = *(const bf16x8*)&abf[arow*MSTR + ks*32 + ak8];
      #pragma unroll
      for (int t = 0; t < 4; ++t) {
        const int nt = wv*4 + t;
        f32x4 acc = {0.f,0.f,0.f,0.f};
        #pragma unroll
        for (int ks = 0; ks < 2; ++ks)
          acc = __builtin_amdgcn_mfma_f32_16x16x32_bf16(
                  ae[ks], get_ba<USE_WS>(wsf, Wa, nt, ks, l), acc, 0, 0, 0);
        #pragma unroll
        for (int j = 0; j < 4; ++j) {
          const int g = (l>>4)*4 + j;
          if (g < 5) att[g*ASTR + nt*16 + arow] = fsigm(acc[j] + bav[t]);
        }
      }
    }
    __syncthreads();                                   // barrier 4: E -> F (att cross-wave)

    // ---- Phase F: out[k][c] = x[k][c] * att[GOF[k]][c]  (x re-read, L2-hot) ----
    {
      float a5[5];
      #pragma unroll
      for (int g = 0; g < 5; ++g) a5[g] = att[g*ASTR + tid];
      const float* xg = x   + (size_t)batch*4352 + tid;
      float*       og = out + (size_t)batch*4352 + tid;
      constexpr int GOF[17] = {0,0,0,0,0,1,2,1,2,1,2,3,4,3,4,3,4};
      #pragma unroll
      for (int k = 0; k < 17; ++k)
        og[k*256] = xg[k*256] * a5[GOF[k]];
    }
    // no end barrier: next stage writes only xbf (last read before barrier 2);
    // att reads here are protected by barriers 1..3 of the next iteration.
  }
}

extern "C" void kernel_launch(void* const* d_in, const int* in_sizes, int n_in,
                              void* d_out, int out_size, void* d_ws, size_t ws_size,
                              hipStream_t stream) {
    (void)n_in; (void)out_size;
    const float* x   = (const float*)d_in[0];
    const float* Wd  = (const float*)d_in[1];
    const float* bd  = (const float*)d_in[2];
    const float* s1  = (const float*)d_in[3];
    const float* b1  = (const float*)d_in[4];
    const float* m1  = (const float*)d_in[5];
    const float* v1  = (const float*)d_in[6];
    const float* Wc  = (const float*)d_in[7];
    const float* s2  = (const float*)d_in[8];
    const float* b2  = (const float*)d_in[9];
    const float* m2  = (const float*)d_in[10];
    const float* v2  = (const float*)d_in[11];
    const float* Wa  = (const float*)d_in[12];
    const float* ba  = (const float*)d_in[13];

    const int Btot = in_sizes[0] / (17 * 256);   // 4096
    const int GRID = Btot / NBAT;                // 1024 blocks (4 per CU, all resident)
    bf16x8* wsf = (bf16x8*)d_ws;

    if (ws_size >= (size_t)FRAG_SLOTS * 16) {
        pack_frags<<<FRAG_SLOTS/256, 256, 0, stream>>>(Wd, Wc, Wa, wsf);
        fused_gnn_v5<true><<<GRID, 256, 0, stream>>>(
            x, Wd, bd, s1, b1, m1, v1, Wc, s2, b2, m2, v2, Wa, ba,
            wsf, (float*)d_out, NBAT);
    } else {
        fused_gnn_v5<false><<<GRID, 256, 0, stream>>>(
            x, Wd, bd, s1, b1, m1, v1, Wc, s2, b2, m2, v2, Wa, ba,
            wsf, (float*)d_out, NBAT);
    }
}

// Round 7
// 48.568 us; speedup vs baseline: 1.9180x; 1.9180x over previous
//
#include <hip/hip_runtime.h>

typedef float  v4f    __attribute__((ext_vector_type(4)));
typedef float  f32x4  __attribute__((ext_vector_type(4)));
typedef short  bf16x8 __attribute__((ext_vector_type(8)));
typedef short  bf16x4 __attribute__((ext_vector_type(4)));

namespace {
constexpr int XBSTR = 264;   // xbf row stride (bf16)
constexpr int XDSTR = 66;    // xd row stride (f32)
constexpr int MWSTR = 132;   // mw row stride (f32)
constexpr int ASTR  = 258;   // att row stride (f32)
constexpr int MSTR  = 72;    // mbf/abf row stride (bf16)
constexpr int NB    = 8;     // batches per block
constexpr int NIT   = 2;     // iterations of 4 batches
constexpr int FRAG_SLOTS = 5120;

// LDS byte offsets (dynamic shared; total 73,120 B -> 2 blocks/CU)
constexpr int OFF_XBF = 0;           // bf16 [80][264] = 42240 (rows 68-79: MFMA tail garbage)
constexpr int OFF_UNI = 42240;       // f32 union: xd[68][66] | mw[20][132] | att[20][258] = 20640
constexpr int OFF_MBF = 62880;       // bf16 [32][72] = 4608 (rows 20-31 garbage)
constexpr int OFF_ABF = 67488;       // bf16 [32][72] = 4608
constexpr int OFF_A1  = 72096;       // f32[64] x4 BN tables
constexpr int OFF_B1  = 72352;
constexpr int OFF_A2  = 72608;
constexpr int OFF_B2  = 72864;
constexpr int LDS_BYTES = 73120;

__device__ __forceinline__ float fsilu(float v){ return v/(1.f+__expf(-v)); }
__device__ __forceinline__ float fsigm(float v){ return 1.f/(1.f+__expf(-v)); }
__device__ __forceinline__ short f2bf(float f){          // fp32 -> bf16 RNE
  unsigned u = __builtin_bit_cast(unsigned, f);
  return (short)((u + 0x7FFFu + ((u>>16)&1u)) >> 16);
}
__device__ __forceinline__ float bf2f(short s){
  unsigned u = ((unsigned)(unsigned short)s) << 16;
  return __builtin_bit_cast(float, u);
}

// ---- B-fragment getters: frag table in ws (fast) or on-the-fly (fallback) ----
template<bool USE_WS>
__device__ __forceinline__ bf16x8 get_bd(const bf16x8* wsf, const float* Wd,
                                         int nt, int ks, int l){
  if constexpr (USE_WS) return wsf[(nt*8 + ks)*64 + l];
  bf16x8 f;
  #pragma unroll
  for (int j = 0; j < 8; ++j) f[j] = f2bf(Wd[(ks*32 + (l>>4)*8 + j)*64 + nt*16 + (l&15)]);
  return f;
}
template<bool USE_WS>
__device__ __forceinline__ bf16x8 get_bc(const bf16x8* wsf, const float* Wc,
                                         int nt, int ks, int l){
  if constexpr (USE_WS) return wsf[2048 + (nt*2 + ks)*64 + l];
  const int col = nt*16 + (l&15), cw = col>>6, co = col&63;
  bf16x8 f;
  #pragma unroll
  for (int j = 0; j < 8; ++j) f[j] = f2bf(Wc[co*128 + cw*64 + ks*32 + (l>>4)*8 + j]);
  return f;
}
template<bool USE_WS>
__device__ __forceinline__ bf16x8 get_ba(const bf16x8* wsf, const float* Wa,
                                         int nt, int ks, int l){
  if constexpr (USE_WS) return wsf[3072 + (nt*2 + ks)*64 + l];
  const int col = nt*16 + (l&15);
  bf16x8 f;
  #pragma unroll
  for (int j = 0; j < 8; ++j) f[j] = f2bf(Wa[(ks*32 + (l>>4)*8 + j)*256 + col]);
  return f;
}
}

// ---- pre-kernel: pack Wd/Wc/Wa into bf16 MFMA B-fragment tables in ws ----
__global__ __launch_bounds__(256)
void pack_frags(const float* __restrict__ Wd, const float* __restrict__ Wc,
                const float* __restrict__ Wa, bf16x8* __restrict__ wsf)
{
  const int e  = blockIdx.x*256 + threadIdx.x;      // 0..5119
  const int l  = e & 63;
  const int fi = e >> 6;                            // 0..79
  bf16x8 f;
  if (fi < 32) {                                    // Bd: nt(4) x ks(8)
    const int nt = fi >> 3, ks = fi & 7;
    #pragma unroll
    for (int j = 0; j < 8; ++j) f[j] = f2bf(Wd[(ks*32 + (l>>4)*8 + j)*64 + nt*16 + (l&15)]);
  } else if (fi < 48) {                             // Bc: nt(8) x ks(2)
    const int idx = fi - 32, nt = idx >> 1, ks = idx & 1;
    const int col = nt*16 + (l&15), cw = col>>6, co = col&63;
    #pragma unroll
    for (int j = 0; j < 8; ++j) f[j] = f2bf(Wc[co*128 + cw*64 + ks*32 + (l>>4)*8 + j]);
  } else {                                          // Ba: nt(16) x ks(2)
    const int idx = fi - 48, nt = idx >> 1, ks = idx & 1;
    const int col = nt*16 + (l&15);
    #pragma unroll
    for (int j = 0; j < 8; ++j) f[j] = f2bf(Wa[(ks*32 + (l>>4)*8 + j)*256 + col]);
  }
  wsf[e] = f;
}

template<bool USE_WS>
__global__ __launch_bounds__(1024)
void fused_gnn_v6(const float* __restrict__ x,
                  const float* __restrict__ Wd, const float* __restrict__ bd,
                  const float* __restrict__ bn1s, const float* __restrict__ bn1b,
                  const float* __restrict__ bn1m, const float* __restrict__ bn1v,
                  const float* __restrict__ Wc,
                  const float* __restrict__ bn2s, const float* __restrict__ bn2b,
                  const float* __restrict__ bn2m, const float* __restrict__ bn2v,
                  const float* __restrict__ Wa, const float* __restrict__ ba,
                  const bf16x8* __restrict__ wsf,
                  float* __restrict__ out)
{
  extern __shared__ char smem[];
  short* xbf = (short*)(smem + OFF_XBF);
  float* xd  = (float*)(smem + OFF_UNI);
  float* mw  = (float*)(smem + OFF_UNI);
  float* att = (float*)(smem + OFF_UNI);
  short* mbf = (short*)(smem + OFF_MBF);
  short* abf = (short*)(smem + OFF_ABF);
  float* a1c = (float*)(smem + OFF_A1);
  float* b1c = (float*)(smem + OFF_B1);
  float* a2c = (float*)(smem + OFF_A2);
  float* b2c = (float*)(smem + OFF_B2);

  const int tid  = threadIdx.x;
  const int l    = tid & 63;
  const int wv   = tid >> 6;            // wave 0..15
  const int arow = l & 15;
  const int ak8  = (l >> 4) * 8;

  // ---- one-time: fold BN affines (b_down folded into bn1 bias) ----
  if (tid < 64) {
    float av = bn1s[tid] * rsqrtf(bn1v[tid] + 1e-5f);
    a1c[tid] = av; b1c[tid] = (bd[tid] - bn1m[tid])*av + bn1b[tid];
    float av2 = bn2s[tid] * rsqrtf(bn2v[tid] + 1e-5f);
    a2c[tid] = av2; b2c[tid] = bn2b[tid] - bn2m[tid]*av2;
  }

  // ---- one-time: persistent weight fragments (v3 layout) ----
  const int ntA  = wv & 3;               // phase A n-tile
  const int colA = ntA*16 + arow;
  bf16x8 Bd[8];
  #pragma unroll
  for (int ks = 0; ks < 8; ++ks) Bd[ks] = get_bd<USE_WS>(wsf, Wd, ntA, ks, l);
  const int ntC  = wv & 7;               // phase B2 n-tile (N=128)
  const int colC = ntC*16 + arow;
  bf16x8 Bc[2];
  #pragma unroll
  for (int ks = 0; ks < 2; ++ks) Bc[ks] = get_bc<USE_WS>(wsf, Wc, ntC, ks, l);
  const int colE = wv*16 + arow;         // phase E n-tile (N=256)
  bf16x8 Ba[2];
  #pragma unroll
  for (int ks = 0; ks < 2; ++ks) Ba[ks] = get_ba<USE_WS>(wsf, Wa, wv, ks, l);
  const float bav = ba[colE];

  // ---- T14 prefetch: first 4-batch group (4352 float4 / 1024 threads) ----
  const v4f* x4 = (const v4f*)x;
  v4f xr0, xr1, xr2, xr3, xr4;
  {
    const size_t b4 = (size_t)(blockIdx.x*NB) * 1088;
    xr0 = x4[b4 + tid];        xr1 = x4[b4 + 1024 + tid];
    xr2 = x4[b4 + 2048 + tid]; xr3 = x4[b4 + 3072 + tid];
    if (tid < 256) xr4 = x4[b4 + 4096 + tid];
  }

  for (int it = 0; it < NIT; ++it) {
    // ---- stage regs -> bf16 LDS (single copy; one conversion per element) ----
    {
      auto store4 = [&](v4f v, int e){
        const int r = e >> 6, c4 = (e & 63) * 4;
        bf16x4 b; b[0]=f2bf(v.x); b[1]=f2bf(v.y); b[2]=f2bf(v.z); b[3]=f2bf(v.w);
        *(bf16x4*)&xbf[r*XBSTR + c4] = b;
      };
      store4(xr0, tid);        store4(xr1, 1024 + tid);
      store4(xr2, 2048 + tid); store4(xr3, 3072 + tid);
      if (tid < 256) store4(xr4, 4096 + tid);
    }
    // issue next group's loads (overlap with this iteration's compute)
    if (it + 1 < NIT) {
      const size_t b4 = (size_t)(blockIdx.x*NB + (it+1)*4) * 1088;
      xr0 = x4[b4 + tid];        xr1 = x4[b4 + 1024 + tid];
      xr2 = x4[b4 + 2048 + tid]; xr3 = x4[b4 + 3072 + tid];
      if (tid < 256) xr4 = x4[b4 + 4096 + tid];
    }
    __syncthreads();                                   // 1: stage -> A

    // ---- Phase A (MFMA): xd = silu(bn1(x @ Wd)), M=68, N=64, K=256 ----
    {
      const int mt = wv >> 2;                          // m-tile 0..3 (rows 0..63)
      f32x4 acc0 = {0.f,0.f,0.f,0.f};
      #pragma unroll
      for (int ks = 0; ks < 8; ++ks) {
        bf16x8 a0 = *(const bf16x8*)&xbf[(mt*16 + arow)*XBSTR + ks*32 + ak8];
        acc0 = __builtin_amdgcn_mfma_f32_16x16x32_bf16(a0, Bd[ks], acc0, 0, 0, 0);
      }
      f32x4 acc1 = {0.f,0.f,0.f,0.f};
      if (wv < 4) {                                    // tail tile rows 64..79 (68-79 garbage)
        #pragma unroll
        for (int ks = 0; ks < 8; ++ks) {
          bf16x8 a1 = *(const bf16x8*)&xbf[(64 + arow)*XBSTR + ks*32 + ak8];
          acc1 = __builtin_amdgcn_mfma_f32_16x16x32_bf16(a1, Bd[ks], acc1, 0, 0, 0);
        }
      }
      const float av = a1c[colA], bv = b1c[colA];
      #pragma unroll
      for (int j = 0; j < 4; ++j) {
        const int r = mt*16 + (l>>4)*4 + j;            // <= 63
        xd[r*XDSTR + colA] = fsilu(acc0[j]*av + bv);
      }
      if (wv < 4) {
        #pragma unroll
        for (int j = 0; j < 4; ++j) {
          const int r = 64 + (l>>4)*4 + j;
          if (r < 68) xd[r*XDSTR + colA] = fsilu(acc1[j]*av + bv);
        }
      }
    }
    __syncthreads();                                   // 2: A -> B1

    // ---- Phase B1: group means -> bf16 (rows qg = q*5+g, 20 total) ----
    #pragma unroll
    for (int pass = 0; pass < 2; ++pass) {
      const int u = pass*1024 + tid;
      if (u < 1280) {
        const int qg = u >> 6, i = u & 63;
        const int q = qg / 5, g = qg - q*5;
        const int rb = q*17;
        float m;
        if (g == 0) {
          m = (xd[(rb+0)*XDSTR+i]+xd[(rb+1)*XDSTR+i]+xd[(rb+2)*XDSTR+i]
              +xd[(rb+3)*XDSTR+i]+xd[(rb+4)*XDSTR+i])*0.2f;
        } else {
          const int kb = rb + ((g==1)?5:(g==2)?6:(g==3)?11:12);
          m = (xd[kb*XDSTR+i] + xd[(kb+2)*XDSTR+i] + xd[(kb+4)*XDSTR+i])*(1.f/3.f);
        }
        mbf[qg*MSTR + i] = f2bf(m);
      }
    }
    __syncthreads();                                   // 3: B1 -> B2

    // ---- Phase B2 (MFMA): mw = means @ [Wc1|Wc2], M=20, N=128, K=64 ----
    {
      const int mt = wv >> 3;                          // 0..1
      f32x4 acc = {0.f,0.f,0.f,0.f};
      #pragma unroll
      for (int ks = 0; ks < 2; ++ks) {
        bf16x8 a = *(const bf16x8*)&mbf[(mt*16 + arow)*MSTR + ks*32 + ak8];
        acc = __builtin_amdgcn_mfma_f32_16x16x32_bf16(a, Bc[ks], acc, 0, 0, 0);
      }
      #pragma unroll
      for (int j = 0; j < 4; ++j) {
        const int qg = mt*16 + (l>>4)*4 + j;
        if (qg < 20) mw[qg*MWSTR + colC] = acc[j];
      }
    }
    __syncthreads();                                   // 4: B2 -> B3

    // ---- Phase B3: agg[qg][o] = sum_{cc!=g} silu(bn2(mw1-mw2[g]+mw2[cc])) ----
    #pragma unroll
    for (int pass = 0; pass < 2; ++pass) {
      const int u = pass*1024 + tid;
      if (u < 1280) {
        const int qg = u >> 6, o = u & 63;
        const int q = qg / 5, g = qg - q*5;
        const float bse = mw[qg*MWSTR + o] - mw[qg*MWSTR + 64 + o];
        const float av = a2c[o], bv = b2c[o];
        float s = 0.f;
        #pragma unroll
        for (int cc = 0; cc < 5; ++cc) {
          if (cc != g) s += fsilu((bse + mw[(q*5+cc)*MWSTR + 64 + o])*av + bv);
        }
        abf[qg*MSTR + o] = f2bf(s);
      }
    }
    __syncthreads();                                   // 5: B3 -> E

    // ---- Phase E (MFMA): att = sigmoid(agg @ Wa + ba), M=20, N=256, K=64 ----
    {
      f32x4 accE0 = {0.f,0.f,0.f,0.f}, accE1 = {0.f,0.f,0.f,0.f};
      #pragma unroll
      for (int ks = 0; ks < 2; ++ks) {
        bf16x8 a0 = *(const bf16x8*)&abf[(arow)*MSTR      + ks*32 + ak8];
        bf16x8 a1 = *(const bf16x8*)&abf[(16 + arow)*MSTR + ks*32 + ak8];
        accE0 = __builtin_amdgcn_mfma_f32_16x16x32_bf16(a0, Ba[ks], accE0, 0, 0, 0);
        accE1 = __builtin_amdgcn_mfma_f32_16x16x32_bf16(a1, Ba[ks], accE1, 0, 0, 0);
      }
      #pragma unroll
      for (int j = 0; j < 4; ++j) {
        const int qg0 = (l>>4)*4 + j;                  // 0..15
        att[qg0*ASTR + colE] = fsigm(accE0[j] + bav);
        const int qg1 = 16 + (l>>4)*4 + j;
        if (qg1 < 20) att[qg1*ASTR + colE] = fsigm(accE1[j] + bav);
      }
    }
    __syncthreads();                                   // 6: E -> F

    // ---- Phase F: out[k][c] = bf16(x)[k][c] * att[q*5+GOF[k]][c] ----
    {
      const int q = tid >> 8, c = tid & 255;
      float a5[5];
      #pragma unroll
      for (int g = 0; g < 5; ++g) a5[g] = att[(q*5+g)*ASTR + c];
      const size_t batch = (size_t)blockIdx.x*NB + it*4 + q;
      float* og = out + batch*4352 + c;
      const int xr = q*17;
      constexpr int GOF[17] = {0,0,0,0,0,1,2,1,2,1,2,3,4,3,4,3,4};
      #pragma unroll
      for (int k = 0; k < 17; ++k)
        og[k*256] = bf2f(xbf[(xr+k)*XBSTR + c]) * a5[GOF[k]];
    }
    __syncthreads();                                   // 7: F -> next stage
  }
}

extern "C" void kernel_launch(void* const* d_in, const int* in_sizes, int n_in,
                              void* d_out, int out_size, void* d_ws, size_t ws_size,
                              hipStream_t stream) {
    (void)n_in; (void)out_size;
    const float* x   = (const float*)d_in[0];
    const float* Wd  = (const float*)d_in[1];
    const float* bd  = (const float*)d_in[2];
    const float* s1  = (const float*)d_in[3];
    const float* b1  = (const float*)d_in[4];
    const float* m1  = (const float*)d_in[5];
    const float* v1  = (const float*)d_in[6];
    const float* Wc  = (const float*)d_in[7];
    const float* s2  = (const float*)d_in[8];
    const float* b2  = (const float*)d_in[9];
    const float* m2  = (const float*)d_in[10];
    const float* v2  = (const float*)d_in[11];
    const float* Wa  = (const float*)d_in[12];
    const float* ba  = (const float*)d_in[13];

    const int Btot = in_sizes[0] / (17 * 256);   // 4096
    const int GRID = Btot / NB;                  // 512 blocks -> 2 per CU, all resident
    bf16x8* wsf = (bf16x8*)d_ws;

    if (ws_size >= (size_t)FRAG_SLOTS * 16) {
        static bool attr_set = false;
        hipFuncSetAttribute(reinterpret_cast<const void*>(&fused_gnn_v6<true>),
                            hipFuncAttributeMaxDynamicSharedMemorySize, LDS_BYTES);
        (void)attr_set;
        pack_frags<<<FRAG_SLOTS/256, 256, 0, stream>>>(Wd, Wc, Wa, wsf);
        fused_gnn_v6<true><<<GRID, 1024, LDS_BYTES, stream>>>(
            x, Wd, bd, s1, b1, m1, v1, Wc, s2, b2, m2, v2, Wa, ba,
            wsf, (float*)d_out);
    } else {
        hipFuncSetAttribute(reinterpret_cast<const void*>(&fused_gnn_v6<false>),
                            hipFuncAttributeMaxDynamicSharedMemorySize, LDS_BYTES);
        fused_gnn_v6<false><<<GRID, 1024, LDS_BYTES, stream>>>(
            x, Wd, bd, s1, b1, m1, v1, Wc, s2, b2, m2, v2, Wa, ba,
            wsf, (float*)d_out);
    }
}